// Round 1
// baseline (6478.742 us; speedup 1.0000x reference)
//
#include <hip/hip_runtime.h>

// ---------------------------------------------------------------------------
// GIN 2-layer: scatter-add aggregation + fused MLP(+BN-stats) + BN apply.
// All fp32 (reference dtypes). Dims: N=50000 nodes, E=1.6M edges, D=128.
// ---------------------------------------------------------------------------

#define D_IN 128
#define D_HID 256
#define TM 16  // rows per MLP block

// --- scatter: agg[dst] += x[src] * w, 32 lanes (float4 each) per edge -------
__global__ __launch_bounds__(256) void scatter_kernel(
    const float* __restrict__ xin, const int* __restrict__ src,
    const int* __restrict__ dst, const float* __restrict__ ew,
    float* __restrict__ agg, int nE)
{
    int tid = blockIdx.x * 256 + threadIdx.x;
    int e = tid >> 5;
    if (e >= nE) return;
    int lane = tid & 31;
    int s = src[e], d = dst[e];
    float w = ew[e];
    float4 v = ((const float4*)xin)[(size_t)s * 32 + lane];
    float* ar = agg + (size_t)d * 128 + lane * 4;
    atomicAdd(ar + 0, v.x * w);
    atomicAdd(ar + 1, v.y * w);
    atomicAdd(ar + 2, v.z * w);
    atomicAdd(ar + 3, v.w * w);
}

// --- fused MLP layer 1: h=agg+x; out = relu(relu(h@Wa+ba)@Wb+bb); + colsums -
__global__ __launch_bounds__(256) void mlp_hid_kernel(
    const float* __restrict__ xin, const float* __restrict__ agg,
    const float* __restrict__ Wa, const float* __restrict__ ba,
    const float* __restrict__ Wb, const float* __restrict__ bb,
    float* __restrict__ out, float* __restrict__ csum, float* __restrict__ csq,
    int N)
{
    __shared__ float hs[TM * 128];       // 8 KB
    __shared__ float inter[TM * 256];    // 16 KB
    __shared__ float red[4 * 128];       // 2 KB
    __shared__ float redq[4 * 128];      // 2 KB

    const int tid = threadIdx.x;
    const int row0 = blockIdx.x * TM;

    // load hs = agg + x (float4)
    for (int i = tid; i < TM * 32; i += 256) {
        int r = i >> 5, k4 = i & 31;
        int row = row0 + r;
        float4 hv = make_float4(0.f, 0.f, 0.f, 0.f);
        if (row < N) {
            float4 av = ((const float4*)agg)[(size_t)row * 32 + k4];
            float4 xv = ((const float4*)xin)[(size_t)row * 32 + k4];
            hv = make_float4(av.x + xv.x, av.y + xv.y, av.z + xv.z, av.w + xv.w);
        }
        ((float4*)hs)[i] = hv;
    }
    __syncthreads();

    // phase 1: [TM,128] @ [128,256] + ba, relu -> inter
    {
        const int jc = tid & 127;    // cols jc, jc+128
        const int rh = tid >> 7;     // rows rh*8 .. rh*8+7
        float acc0[8], acc1[8];
        float b0 = ba[jc], b1 = ba[jc + 128];
        #pragma unroll
        for (int r = 0; r < 8; ++r) { acc0[r] = b0; acc1[r] = b1; }
        for (int k4 = 0; k4 < 32; ++k4) {
            float4 hv[8];
            #pragma unroll
            for (int r = 0; r < 8; ++r)
                hv[r] = ((const float4*)hs)[(rh * 8 + r) * 32 + k4];
            #pragma unroll
            for (int kk = 0; kk < 4; ++kk) {
                int k = k4 * 4 + kk;
                float w0 = Wa[k * 256 + jc];
                float w1 = Wa[k * 256 + jc + 128];
                #pragma unroll
                for (int r = 0; r < 8; ++r) {
                    float h = (kk == 0) ? hv[r].x : (kk == 1) ? hv[r].y
                              : (kk == 2) ? hv[r].z : hv[r].w;
                    acc0[r] += h * w0;
                    acc1[r] += h * w1;
                }
            }
        }
        #pragma unroll
        for (int r = 0; r < 8; ++r) {
            inter[(rh * 8 + r) * 256 + jc]       = fmaxf(acc0[r], 0.f);
            inter[(rh * 8 + r) * 256 + jc + 128] = fmaxf(acc1[r], 0.f);
        }
    }
    __syncthreads();

    // phase 2: [TM,256] @ [256,128] + bb, relu -> out; column partial sums
    {
        const int j2 = tid & 63;     // cols j2, j2+64
        const int rh2 = tid >> 6;    // rows rh2*4 .. rh2*4+3
        float acc0[4], acc1[4];
        float b0 = bb[j2], b1 = bb[j2 + 64];
        #pragma unroll
        for (int r = 0; r < 4; ++r) { acc0[r] = b0; acc1[r] = b1; }
        for (int k4 = 0; k4 < 64; ++k4) {
            float4 iv[4];
            #pragma unroll
            for (int r = 0; r < 4; ++r)
                iv[r] = ((const float4*)inter)[(rh2 * 4 + r) * 64 + k4];
            #pragma unroll
            for (int kk = 0; kk < 4; ++kk) {
                int k = k4 * 4 + kk;
                float w0 = Wb[k * 128 + j2];
                float w1 = Wb[k * 128 + j2 + 64];
                #pragma unroll
                for (int r = 0; r < 4; ++r) {
                    float h = (kk == 0) ? iv[r].x : (kk == 1) ? iv[r].y
                              : (kk == 2) ? iv[r].z : iv[r].w;
                    acc0[r] += h * w0;
                    acc1[r] += h * w1;
                }
            }
        }
        float vs0 = 0.f, vq0 = 0.f, vs1 = 0.f, vq1 = 0.f;
        #pragma unroll
        for (int r = 0; r < 4; ++r) {
            int row = row0 + rh2 * 4 + r;
            float v0 = fmaxf(acc0[r], 0.f);
            float v1 = fmaxf(acc1[r], 0.f);
            if (row < N) {
                out[(size_t)row * 128 + j2]      = v0;
                out[(size_t)row * 128 + j2 + 64] = v1;
                vs0 += v0; vq0 += v0 * v0;
                vs1 += v1; vq1 += v1 * v1;
            }
        }
        red [rh2 * 128 + j2]      = vs0;
        red [rh2 * 128 + j2 + 64] = vs1;
        redq[rh2 * 128 + j2]      = vq0;
        redq[rh2 * 128 + j2 + 64] = vq1;
    }
    __syncthreads();
    if (tid < 128) {
        float s = red[tid] + red[128 + tid] + red[256 + tid] + red[384 + tid];
        float q = redq[tid] + redq[128 + tid] + redq[256 + tid] + redq[384 + tid];
        atomicAdd(&csum[tid], s);
        atomicAdd(&csq[tid], q);
    }
}

// --- fused MLP layer 2: out dim 2 -------------------------------------------
__global__ __launch_bounds__(256) void mlp_out2_kernel(
    const float* __restrict__ xin, const float* __restrict__ agg,
    const float* __restrict__ Wa, const float* __restrict__ ba,
    const float* __restrict__ Wb, const float* __restrict__ bb,
    float* __restrict__ out, float* __restrict__ csum, float* __restrict__ csq,
    int N)
{
    __shared__ float hs[TM * 128];
    __shared__ float inter[TM * 256];

    const int tid = threadIdx.x;
    const int row0 = blockIdx.x * TM;

    for (int i = tid; i < TM * 32; i += 256) {
        int r = i >> 5, k4 = i & 31;
        int row = row0 + r;
        float4 hv = make_float4(0.f, 0.f, 0.f, 0.f);
        if (row < N) {
            float4 av = ((const float4*)agg)[(size_t)row * 32 + k4];
            float4 xv = ((const float4*)xin)[(size_t)row * 32 + k4];
            hv = make_float4(av.x + xv.x, av.y + xv.y, av.z + xv.z, av.w + xv.w);
        }
        ((float4*)hs)[i] = hv;
    }
    __syncthreads();

    // phase 1: identical to layer 1 (128 -> 256, relu)
    {
        const int jc = tid & 127;
        const int rh = tid >> 7;
        float acc0[8], acc1[8];
        float b0 = ba[jc], b1 = ba[jc + 128];
        #pragma unroll
        for (int r = 0; r < 8; ++r) { acc0[r] = b0; acc1[r] = b1; }
        for (int k4 = 0; k4 < 32; ++k4) {
            float4 hv[8];
            #pragma unroll
            for (int r = 0; r < 8; ++r)
                hv[r] = ((const float4*)hs)[(rh * 8 + r) * 32 + k4];
            #pragma unroll
            for (int kk = 0; kk < 4; ++kk) {
                int k = k4 * 4 + kk;
                float w0 = Wa[k * 256 + jc];
                float w1 = Wa[k * 256 + jc + 128];
                #pragma unroll
                for (int r = 0; r < 8; ++r) {
                    float h = (kk == 0) ? hv[r].x : (kk == 1) ? hv[r].y
                              : (kk == 2) ? hv[r].z : hv[r].w;
                    acc0[r] += h * w0;
                    acc1[r] += h * w1;
                }
            }
        }
        #pragma unroll
        for (int r = 0; r < 8; ++r) {
            inter[(rh * 8 + r) * 256 + jc]       = fmaxf(acc0[r], 0.f);
            inter[(rh * 8 + r) * 256 + jc + 128] = fmaxf(acc1[r], 0.f);
        }
    }
    __syncthreads();

    // phase 2: [TM,256] @ [256,2] + bb, relu -> out; column sums via shuffle
    if (tid < 32) {
        int r = tid >> 1, j2 = tid & 1;
        float acc = bb[j2];
        for (int k4 = 0; k4 < 64; ++k4) {
            float4 iv = ((const float4*)inter)[r * 64 + k4];
            acc += iv.x * Wb[(k4 * 4 + 0) * 2 + j2];
            acc += iv.y * Wb[(k4 * 4 + 1) * 2 + j2];
            acc += iv.z * Wb[(k4 * 4 + 2) * 2 + j2];
            acc += iv.w * Wb[(k4 * 4 + 3) * 2 + j2];
        }
        float v = fmaxf(acc, 0.f);
        int row = row0 + r;
        float vs = 0.f, vq = 0.f;
        if (row < N) {
            out[(size_t)row * 2 + j2] = v;
            vs = v; vq = v * v;
        }
        // reduce over the 16 rows (same-parity lanes), lanes 0/1 hold totals
        #pragma unroll
        for (int off = 16; off >= 2; off >>= 1) {
            vs += __shfl_down(vs, off, 64);
            vq += __shfl_down(vq, off, 64);
        }
        if (tid < 2) {
            atomicAdd(&csum[j2], vs);
            atomicAdd(&csq[j2], vq);
        }
    }
}

// --- BN apply, 128 features, in-place ---------------------------------------
__global__ __launch_bounds__(256) void bn_apply128_kernel(
    float* __restrict__ a, const float* __restrict__ cs,
    const float* __restrict__ cq, const float* __restrict__ gamma,
    const float* __restrict__ beta, int N)
{
    int i = blockIdx.x * 256 + threadIdx.x;  // float4 index
    int total = N * 32;
    if (i >= total) return;
    int j0 = (i & 31) * 4;
    float invN = 1.0f / (float)N;
    float4 v = ((const float4*)a)[i];
    float o[4] = {v.x, v.y, v.z, v.w};
    #pragma unroll
    for (int c = 0; c < 4; ++c) {
        int j = j0 + c;
        float mean = cs[j] * invN;
        float var = cq[j] * invN - mean * mean;
        float scale = gamma[j] * rsqrtf(var + 1e-5f);
        o[c] = (o[c] - mean) * scale + beta[j];
    }
    ((float4*)a)[i] = make_float4(o[0], o[1], o[2], o[3]);
}

// --- BN apply, 2 features, writes d_out -------------------------------------
__global__ __launch_bounds__(256) void bn_apply2_kernel(
    const float* __restrict__ a, const float* __restrict__ cs,
    const float* __restrict__ cq, const float* __restrict__ gamma,
    const float* __restrict__ beta, float* __restrict__ out, int N)
{
    int i = blockIdx.x * 256 + threadIdx.x;
    if (i >= N * 2) return;
    int j = i & 1;
    float invN = 1.0f / (float)N;
    float mean = cs[j] * invN;
    float var = cq[j] * invN - mean * mean;
    float scale = gamma[j] * rsqrtf(var + 1e-5f);
    out[i] = (a[i] - mean) * scale + beta[j];
}

extern "C" void kernel_launch(void* const* d_in, const int* in_sizes, int n_in,
                              void* d_out, int out_size, void* d_ws, size_t ws_size,
                              hipStream_t stream)
{
    const float* x   = (const float*)d_in[0];
    const int*   ei  = (const int*)  d_in[1];
    // d_in[2] = edge_attr, unused by reference
    const float* ew  = (const float*)d_in[3];
    const float* W1a = (const float*)d_in[4];
    const float* b1a = (const float*)d_in[5];
    const float* W1b = (const float*)d_in[6];
    const float* b1b = (const float*)d_in[7];
    const float* g1  = (const float*)d_in[8];
    const float* be1 = (const float*)d_in[9];
    const float* W2a = (const float*)d_in[10];
    const float* b2a = (const float*)d_in[11];
    const float* W2b = (const float*)d_in[12];
    const float* b2b = (const float*)d_in[13];
    const float* g2  = (const float*)d_in[14];
    const float* be2 = (const float*)d_in[15];

    const int N = in_sizes[0] / 128;
    const int E = in_sizes[3];
    const int* src = ei;
    const int* dst = ei + E;

    float* agg = (float*)d_ws;                       // N*128
    float* a1  = agg + (size_t)N * 128;              // N*128 (becomes h1 in place)
    float* a2  = a1  + (size_t)N * 128;              // N*2
    float* st  = a2  + (size_t)N * 2;                // 260 stats floats
    float* cs1 = st;        // 128
    float* cq1 = st + 128;  // 128
    float* cs2 = st + 256;  // 2
    float* cq2 = st + 258;  // 2

    const int nScatterBlk = (E * 32 + 255) / 256;
    const int nMlpBlk = (N + TM - 1) / TM;

    // ---- layer 1 ----
    hipMemsetAsync(agg, 0, (size_t)N * 128 * sizeof(float), stream);
    hipMemsetAsync(st, 0, 260 * sizeof(float), stream);
    scatter_kernel<<<nScatterBlk, 256, 0, stream>>>(x, src, dst, ew, agg, E);
    mlp_hid_kernel<<<nMlpBlk, 256, 0, stream>>>(x, agg, W1a, b1a, W1b, b1b,
                                                a1, cs1, cq1, N);
    bn_apply128_kernel<<<(N * 32 + 255) / 256, 256, 0, stream>>>(a1, cs1, cq1,
                                                                 g1, be1, N);
    // ---- layer 2 ----
    hipMemsetAsync(agg, 0, (size_t)N * 128 * sizeof(float), stream);
    scatter_kernel<<<nScatterBlk, 256, 0, stream>>>(a1, src, dst, ew, agg, E);
    mlp_out2_kernel<<<nMlpBlk, 256, 0, stream>>>(a1, agg, W2a, b2a, W2b, b2b,
                                                 a2, cs2, cq2, N);
    bn_apply2_kernel<<<(N * 2 + 255) / 256, 256, 0, stream>>>(a2, cs2, cq2,
                                                              g2, be2,
                                                              (float*)d_out, N);
}